// Round 9
// baseline (161.004 us; speedup 1.0000x reference)
//
#include <hip/hip_runtime.h>
#include <hip/hip_bf16.h>
#include <math.h>

#define NBINS 10
#define NVALS 21          // 0:bce, 1..10:counts, 11..20:sum(p-t)
#define THREADS 256
#define HSTRIDE 11        // words/thread; gcd(11,32)=1 -> 2-way bases (free)

typedef float v4f __attribute__((ext_vector_type(4)));

__device__ __forceinline__ v4f ntload(const v4f* p) {
  return __builtin_nontemporal_load(p);   // global_load_dwordx4 ... nt
}

// Minimal-VALU per-element work (proven best in R4/R7):
//  - sums: single b32 LDS RMW into private stride-11 slot
//  - counts: packed 6-bit fields in one u64 VGPR, flushed every round
__device__ __forceinline__ void proc(float x0, float t0, float& bce_acc,
                                     unsigned long long& c6,
                                     float* __restrict__ my) {
  bool valid = (x0 == x0) && (t0 == t0);
  float t = __builtin_amdgcn_fmed3f(t0, 0.f, 1.f);
  float e = __expf(-fabsf(x0));                 // exp(-|x|)
  float L = 1.f + e;
  float r = __builtin_amdgcn_rcpf(L);
  float p = (x0 >= 0.f) ? r : e * r;            // sigmoid(x); NaN-in -> NaN
  float l2p = __log2f(p);
  const float NLN2 = -0.6931471805599453f;
  float coef2 = __builtin_fmaf(79.f * NLN2, t, NLN2);  // -(80t+1-t)ln2
  float omtx = __builtin_fmaf(-t, x0, x0);             // (1-t)x
  float b = __builtin_fmaf(coef2, l2p, omtx);
  bce_acc += valid ? b : 0.f;

  int ib = (int)(p * 10.f);                     // NaN -> 0 (masked below)
  ib = ib > 9 ? 9 : ib;
  float d = valid ? (p - t) : 0.f;
  my[ib] += d;                                  // ds_read_b32+add+ds_write_b32
  unsigned inc = valid ? 1u : 0u;
  c6 += (unsigned long long)inc << (unsigned)(ib * 6);
}

__device__ __forceinline__ void proc4(v4f xv, v4f tv, float& bce,
                                      unsigned long long& c6, float* my) {
  proc(xv[0], tv[0], bce, c6, my);
  proc(xv[1], tv[1], bce, c6, my);
  proc(xv[2], tv[2], bce, c6, my);
  proc(xv[3], tv[3], bce, c6, my);
}

__global__ __launch_bounds__(THREADS, 6) void dl_partial(
    const float* __restrict__ pred, const float* __restrict__ targ,
    long long n, float* __restrict__ ws, int grid) {
  __shared__ float hist[THREADS * HSTRIDE];   // 11264 B
  __shared__ float red[4][NVALS];

  const int tid = threadIdx.x;
  float* my = hist + tid * HSTRIDE;
#pragma unroll
  for (int b = 0; b < NBINS; ++b) my[b] = 0.f;

  const long long gid = (long long)blockIdx.x * THREADS + tid;
  const long long s = (long long)grid * THREADS;   // layer stride in float4s
  const long long nvec = n >> 2;

  float bce = 0.f;
  unsigned long long c6 = 0ull;
  unsigned cnt[NBINS];
#pragma unroll
  for (int b = 0; b < NBINS; ++b) cnt[b] = 0u;

  const v4f* p4 = (const v4f*)pred;
  const v4f* t4 = (const v4f*)targ;

  // 4-deep rotating buffer; loads go DIRECTLY into named slot registers so
  // 6-8 dwordx4 stay in flight per wave at all times (no temp-copy waits).
  const long long R = nvec / (4 * s);          // complete rounds (all slots in-range)
  v4f X0{}, T0{}, X1{}, T1{}, X2{}, T2{}, X3{}, T3{};
  long long i = gid;
  if (R > 0) {
    X0 = ntload(p4 + i);           T0 = ntload(t4 + i);
    X1 = ntload(p4 + i + s);       T1 = ntload(t4 + i + s);
    X2 = ntload(p4 + i + 2 * s);   T2 = ntload(t4 + i + 2 * s);
    X3 = ntload(p4 + i + 3 * s);   T3 = ntload(t4 + i + 3 * s);
    for (long long rr = 0; rr + 1 < R; ++rr) {
      // stage k: consume slot k (loaded 4 layers ago), refill from 4 ahead
      proc4(X0, T0, bce, c6, my);
      X0 = ntload(p4 + i + 4 * s); T0 = ntload(t4 + i + 4 * s);
      proc4(X1, T1, bce, c6, my);
      X1 = ntload(p4 + i + 5 * s); T1 = ntload(t4 + i + 5 * s);
      proc4(X2, T2, bce, c6, my);
      X2 = ntload(p4 + i + 6 * s); T2 = ntload(t4 + i + 6 * s);
      proc4(X3, T3, bce, c6, my);
      X3 = ntload(p4 + i + 7 * s); T3 = ntload(t4 + i + 7 * s);
      i += 4 * s;
      // flush packed counts (16 elems/round, cap 63)
#pragma unroll
      for (int b = 0; b < NBINS; ++b)
        cnt[b] += (unsigned)((c6 >> (6 * b)) & 63ull);
      c6 = 0ull;
    }
    // final full round: no refill
    proc4(X0, T0, bce, c6, my);
    proc4(X1, T1, bce, c6, my);
    proc4(X2, T2, bce, c6, my);
    proc4(X3, T3, bce, c6, my);
#pragma unroll
    for (int b = 0; b < NBINS; ++b)
      cnt[b] += (unsigned)((c6 >> (6 * b)) & 63ull);
    c6 = 0ull;
  }
  // remainder float4 layers beyond 4*R*s (guarded grid-stride)
  for (long long j = 4 * R * s + gid; j < nvec; j += s) {
    v4f xv = ntload(p4 + j), tv = ntload(t4 + j);
    proc4(xv, tv, bce, c6, my);
  }
  // scalar remainder (n % 4)
  long long ti = (nvec << 2) + gid;
  if (ti < n) proc(pred[ti], targ[ti], bce, c6, my);
#pragma unroll
  for (int b = 0; b < NBINS; ++b)
    cnt[b] += (unsigned)((c6 >> (6 * b)) & 63ull);

  // pack + wave reduce (own LDS slots: same-wave program order, no barrier)
  float vals[NVALS];
  vals[0] = bce;
#pragma unroll
  for (int b = 0; b < NBINS; ++b) {
    vals[1 + b] = (float)cnt[b];
    vals[11 + b] = my[b];
  }
#pragma unroll
  for (int v = 0; v < NVALS; ++v) {
#pragma unroll
    for (int off = 32; off; off >>= 1) vals[v] += __shfl_xor(vals[v], off, 64);
  }
  const int lane = tid & 63;
  const int wave = tid >> 6;
  if (lane == 0) {
#pragma unroll
    for (int v = 0; v < NVALS; ++v) red[wave][v] = vals[v];
  }
  __syncthreads();
  if (tid < NVALS) {
    float sum = red[0][tid] + red[1][tid] + red[2][tid] + red[3][tid];
    ws[(long long)tid * grid + blockIdx.x] = sum;  // SoA, coalesced final pass
  }
}

__global__ __launch_bounds__(THREADS) void dl_final(
    const float* __restrict__ ws, float* __restrict__ out, int grid) {
  __shared__ double totals[NVALS];
  __shared__ double wred[4];
  const int tid = threadIdx.x;
  for (int r = 0; r < NVALS; ++r) {
    double psum = 0.0;
    for (int i = tid; i < grid; i += THREADS)
      psum += (double)ws[(long long)r * grid + i];
#pragma unroll
    for (int off = 32; off; off >>= 1) psum += __shfl_xor(psum, off, 64);
    if ((tid & 63) == 0) wred[tid >> 6] = psum;
    __syncthreads();
    if (tid == 0) totals[r] = wred[0] + wred[1] + wred[2] + wred[3];
    __syncthreads();
  }
  if (tid == 0) {
    double bce = totals[0];
    double nv = 0.0;
    for (int b = 0; b < NBINS; ++b) nv += totals[1 + b];  // n_valid = sum counts
    double dist = 0.0;
    for (int b = 0; b < NBINS; ++b) {
      double c = totals[1 + b], sd = totals[11 + b];
      double safe = c > 1.0 ? c : 1.0;
      if (c > 10.0) dist += fabs(sd) / safe;
    }
    out[0] = (float)(bce / nv + dist / (double)NBINS * 0.2);
  }
}

extern "C" void kernel_launch(void* const* d_in, const int* in_sizes, int n_in,
                              void* d_out, int out_size, void* d_ws, size_t ws_size,
                              hipStream_t stream) {
  const float* pred = (const float*)d_in[0];
  const float* targ = (const float*)d_in[1];
  const long long n = (long long)in_sizes[0];
  float* out = (float*)d_out;
  float* ws = (float*)d_ws;

  int grid = 2048;  // 16.8M float4 / (2048*256) = 32 layers = 8 full rounds
  while (grid > 64 && (size_t)NVALS * grid * sizeof(float) > ws_size) grid >>= 1;

  dl_partial<<<grid, THREADS, 0, stream>>>(pred, targ, n, ws, grid);
  dl_final<<<1, THREADS, 0, stream>>>(ws, out, grid);
}

// Round 10
// 140.293 us; speedup vs baseline: 1.1476x; 1.1476x over previous
//
#include <hip/hip_runtime.h>
#include <hip/hip_bf16.h>
#include <math.h>

#define NBINS 10
#define NVALS 21          // 0:bce, 1..10:counts, 11..20:sum(p-t)
#define THREADS 256
#define HSTRIDE 11        // words/thread; gcd(11,32)=1 -> 2-way bases (free)

typedef float v4f __attribute__((ext_vector_type(4)));

__device__ __forceinline__ v4f ntload(const v4f* p) {
  return __builtin_nontemporal_load(p);   // nt: stream, don't allocate
}
__device__ __forceinline__ v4f tload(const v4f* p) {
  return *p;                               // temporal: allow L3 residency
}

// Minimal-VALU per-element work (proven best in R4/R7):
//  - sums: single b32 LDS RMW into private stride-11 slot
//  - counts: packed 6-bit fields in one u64 VGPR, flushed periodically
__device__ __forceinline__ void proc(float x0, float t0, float& bce_acc,
                                     unsigned long long& c6,
                                     float* __restrict__ my) {
  bool valid = (x0 == x0) && (t0 == t0);
  float t = __builtin_amdgcn_fmed3f(t0, 0.f, 1.f);
  float e = __expf(-fabsf(x0));                 // exp(-|x|)
  float L = 1.f + e;
  float r = __builtin_amdgcn_rcpf(L);
  float p = (x0 >= 0.f) ? r : e * r;            // sigmoid(x); NaN-in -> NaN
  float l2p = __log2f(p);
  const float NLN2 = -0.6931471805599453f;
  float coef2 = __builtin_fmaf(79.f * NLN2, t, NLN2);  // -(80t+1-t)ln2
  float omtx = __builtin_fmaf(-t, x0, x0);             // (1-t)x
  float b = __builtin_fmaf(coef2, l2p, omtx);
  bce_acc += valid ? b : 0.f;

  int ib = (int)(p * 10.f);                     // NaN -> 0 (masked below)
  ib = ib > 9 ? 9 : ib;
  float d = valid ? (p - t) : 0.f;
  my[ib] += d;                                  // ds_read_b32+add+ds_write_b32
  unsigned inc = valid ? 1u : 0u;
  c6 += (unsigned long long)inc << (unsigned)(ib * 6);
}

__device__ __forceinline__ void proc4(v4f xv, v4f tv, float& bce,
                                      unsigned long long& c6, float* my) {
  proc(xv[0], tv[0], bce, c6, my);
  proc(xv[1], tv[1], bce, c6, my);
  proc(xv[2], tv[2], bce, c6, my);
  proc(xv[3], tv[3], bce, c6, my);
}

__global__ __launch_bounds__(THREADS, 8) void dl_partial(
    const float* __restrict__ pred, const float* __restrict__ targ,
    long long n, float* __restrict__ ws, int grid) {
  __shared__ float hist[THREADS * HSTRIDE];   // 11264 B
  __shared__ float red[4][NVALS];             // -> 8 blocks/CU

  const int tid = threadIdx.x;
  float* my = hist + tid * HSTRIDE;
#pragma unroll
  for (int b = 0; b < NBINS; ++b) my[b] = 0.f;

  const long long gid = (long long)blockIdx.x * THREADS + tid;
  const long long s = (long long)grid * THREADS;   // stride in float4 units
  const long long nvec = n >> 2;

  float bce = 0.f;
  unsigned long long c6 = 0ull;
  unsigned cnt[NBINS];
#pragma unroll
  for (int b = 0; b < NBINS; ++b) cnt[b] = 0u;

  const v4f* p4 = (const v4f*)pred;   // temporal: 256 MiB fits L3
  const v4f* t4 = (const v4f*)targ;   // nontemporal: stream from HBM

  // depth-2 ping-pong prefetch (exact R7 structure; only cache hints differ)
  long long i = gid;
  v4f XA{}, TA{}, XB{}, TB{};
  bool hA = i < nvec;
  if (hA) { XA = tload(p4 + i); TA = ntload(t4 + i); }
  bool hB = (i + s) < nvec;
  if (hB) { XB = tload(p4 + i + s); TB = ntload(t4 + i + s); }
  unsigned it = 0;
  while (hA) {
    bool hp = (i + 2 * s) < nvec;
    {
      v4f px{}, pt{};
      if (hp) { px = tload(p4 + i + 2 * s); pt = ntload(t4 + i + 2 * s); }
      proc4(XA, TA, bce, c6, my);
      XA = px; TA = pt;
    }
    if (hB) {
      bool hq = (i + 3 * s) < nvec;
      v4f px{}, pt{};
      if (hq) { px = tload(p4 + i + 3 * s); pt = ntload(t4 + i + 3 * s); }
      proc4(XB, TB, bce, c6, my);
      XB = px; TB = pt;
      hB = hq;
    }
    hA = hp;
    i += 2 * s;
    if ((++it & 3u) == 0u) {          // every 8 batches = 32 elems (< 63 cap)
#pragma unroll
      for (int b = 0; b < NBINS; ++b)
        cnt[b] += (unsigned)((c6 >> (6 * b)) & 63ull);
      c6 = 0ull;
    }
  }
  // scalar remainder (n % 4)
  long long ti = (nvec << 2) + gid;
  if (ti < n) proc(pred[ti], targ[ti], bce, c6, my);
#pragma unroll
  for (int b = 0; b < NBINS; ++b)
    cnt[b] += (unsigned)((c6 >> (6 * b)) & 63ull);

  // pack + wave reduce (own LDS slots: same-wave program order, no barrier)
  float vals[NVALS];
  vals[0] = bce;
#pragma unroll
  for (int b = 0; b < NBINS; ++b) {
    vals[1 + b] = (float)cnt[b];   // exact (<= 128/thread)
    vals[11 + b] = my[b];
  }
#pragma unroll
  for (int v = 0; v < NVALS; ++v) {
#pragma unroll
    for (int off = 32; off; off >>= 1) vals[v] += __shfl_xor(vals[v], off, 64);
  }
  const int lane = tid & 63;
  const int wave = tid >> 6;
  if (lane == 0) {
#pragma unroll
    for (int v = 0; v < NVALS; ++v) red[wave][v] = vals[v];
  }
  __syncthreads();
  if (tid < NVALS) {
    float sum = red[0][tid] + red[1][tid] + red[2][tid] + red[3][tid];
    ws[(long long)tid * grid + blockIdx.x] = sum;  // SoA, coalesced final pass
  }
}

__global__ __launch_bounds__(THREADS) void dl_final(
    const float* __restrict__ ws, float* __restrict__ out, int grid) {
  __shared__ double totals[NVALS];
  __shared__ double wred[4];
  const int tid = threadIdx.x;
  for (int r = 0; r < NVALS; ++r) {
    double psum = 0.0;
    for (int i = tid; i < grid; i += THREADS)
      psum += (double)ws[(long long)r * grid + i];
#pragma unroll
    for (int off = 32; off; off >>= 1) psum += __shfl_xor(psum, off, 64);
    if ((tid & 63) == 0) wred[tid >> 6] = psum;
    __syncthreads();
    if (tid == 0) totals[r] = wred[0] + wred[1] + wred[2] + wred[3];
    __syncthreads();
  }
  if (tid == 0) {
    double bce = totals[0];
    double nv = 0.0;
    for (int b = 0; b < NBINS; ++b) nv += totals[1 + b];  // n_valid = sum counts
    double dist = 0.0;
    for (int b = 0; b < NBINS; ++b) {
      double c = totals[1 + b], sd = totals[11 + b];
      double safe = c > 1.0 ? c : 1.0;
      if (c > 10.0) dist += fabs(sd) / safe;
    }
    out[0] = (float)(bce / nv + dist / (double)NBINS * 0.2);
  }
}

extern "C" void kernel_launch(void* const* d_in, const int* in_sizes, int n_in,
                              void* d_out, int out_size, void* d_ws, size_t ws_size,
                              hipStream_t stream) {
  const float* pred = (const float*)d_in[0];
  const float* targ = (const float*)d_in[1];
  const long long n = (long long)in_sizes[0];
  float* out = (float*)d_out;
  float* ws = (float*)d_ws;

  int grid = 2048;  // 8 blocks/CU x 256 CUs
  while (grid > 64 && (size_t)NVALS * grid * sizeof(float) > ws_size) grid >>= 1;

  dl_partial<<<grid, THREADS, 0, stream>>>(pred, targ, n, ws, grid);
  dl_final<<<1, THREADS, 0, stream>>>(ws, out, grid);
}